// Round 5
// baseline (33.501 us; speedup 1.0000x reference)
//
#include <hip/hip_runtime.h>

// Shapley fusion — DIAGNOSTIC ROUND (r5): r4's kernel body looped 4x,
// idempotently (identical output each pass). Purpose:
//   p = (dur4 - dur1)/3  -> marginal per-pass cost with cache-hot data
//   F = dur1 - p         -> fixed overhead (launch/ramp/drain)
// and dur4 > 40us makes this kernel visible in the rocprof top-5 rows
// (the harness's 256MB fills otherwise crowd it out), exposing
// FETCH_SIZE / VALUBusy / OccupancyPercent for the real access pattern.
//
// f(subset) = relu(b + sum_{l in subset} d[l]), d[l] = dot(feats[l,:,n], w);
// Shapley coef for L=5 by subset size: {-, -0.6, 0.05, 1/30, 0.05, 0.2}.

constexpr int L_VIEWS = 5;
constexpr int C_CH    = 64;
constexpr int NPIX    = 128 * 256;   // 32768
constexpr int REPEATS = 4;           // diagnostic loop count

__global__ __launch_bounds__(256)
void shapley_fusion_kernel(const float* __restrict__ feats,
                           const float* __restrict__ w,
                           const float* __restrict__ bptr,
                           float* __restrict__ out)
{
    const int tid  = threadIdx.x;
    const int h    = tid >> 6;         // wave in block (0..3): channel quarter
    const int lane = tid & 63;
    const int q    = lane & 7;         // n-quad within the 32-n window
    const int g    = (lane >> 3) & 7;  // channel group within wave
    const int win  = blockIdx.x * 32;  // 128-B aligned n window
    const int nq   = win + q * 4;
    const int cA   = h * 8 + g;        // this thread's 2 channels
    const int cB   = cA + 32;

    const float w0   = w[cA];
    const float w1   = w[cB];
    const float bias = bptr[0];

    __shared__ float4 xl[4][8][L_VIEWS];      // [wave][quad][l] = d[l][0..3]

    for (int it = 0; it < REPEATS; ++it) {
        // Force real reloads each pass (no register-caching across iters).
        asm volatile("" ::: "memory");

        // ---- Phase A: load 10 float4s; per instruction 8 rows x 128-B full
        // lines (q spans 128 B contiguous, g spans 8 rows).
        float4 va[L_VIEWS][2];
#pragma unroll
        for (int l = 0; l < L_VIEWS; ++l) {
            va[l][0] = *reinterpret_cast<const float4*>(
                feats + ((size_t)(l * C_CH + cA) * NPIX + nq));
            va[l][1] = *reinterpret_cast<const float4*>(
                feats + ((size_t)(l * C_CH + cB) * NPIX + nq));
        }

        float d[L_VIEWS][4];
#pragma unroll
        for (int l = 0; l < L_VIEWS; ++l) {
            d[l][0] = va[l][0].x * w0 + va[l][1].x * w1;
            d[l][1] = va[l][0].y * w0 + va[l][1].y * w1;
            d[l][2] = va[l][0].z * w0 + va[l][1].z * w1;
            d[l][3] = va[l][0].w * w0 + va[l][1].w * w1;
        }

        // Butterfly over the 8 channel-groups (lane bits 3..5).
#pragma unroll
        for (int l = 0; l < L_VIEWS; ++l) {
#pragma unroll
            for (int j = 0; j < 4; ++j) {
                d[l][j] += __shfl_xor(d[l][j], 8, 64);
                d[l][j] += __shfl_xor(d[l][j], 16, 64);
                d[l][j] += __shfl_xor(d[l][j], 32, 64);
            }
        }

        // ---- Cross-wave exchange (2.5 KB LDS). ----
        if (it != 0) __syncthreads();   // protect xl reuse across iterations
        if (g == 0) {
#pragma unroll
            for (int l = 0; l < L_VIEWS; ++l) {
                float4 t; t.x = d[l][0]; t.y = d[l][1]; t.z = d[l][2]; t.w = d[l][3];
                xl[h][q][l] = t;
            }
        }
        __syncthreads();

        // Each thread finalizes d only for its own j = g&3.
        const int jm = g & 3;
        const float* xf = reinterpret_cast<const float*>(xl);
        float dm[L_VIEWS];
#pragma unroll
        for (int l = 0; l < L_VIEWS; ++l) {
            float s = 0.f;
#pragma unroll
            for (int hh = 0; hh < 4; ++hh)
                s += xf[(((hh * 8 + q) * L_VIEWS) + l) * 4 + jm];
            dm[l] = s;
        }

        // ---- Phase B: subset lattice -> shapley -> softmax (one j per thread).
        constexpr float WT1 = -0.6f;          // singleton: -(L-2)/L
        constexpr float WT2 = 0.05f;          // 1!*3!/5!
        constexpr float WT3 = 1.0f / 30.0f;   // 2!*2!/5!
        constexpr float WT4 = 0.05f;          // 3!*1!/5!
        constexpr float WT5 = 0.2f;           // 4!*0!/5!

        float s[32];
        s[0] = bias;
        float sh[L_VIEWS] = {0.f, 0.f, 0.f, 0.f, 0.f};
#pragma unroll
        for (int m = 1; m < 32; ++m) {
            const int lb  = m & (-m);
            const int lbi = __builtin_ctz(m);
            s[m] = s[m ^ lb] + dm[lbi];
            const float f = fmaxf(s[m], 0.f);
            const int pc = __builtin_popcount(m);
            const float wt = (pc == 1) ? WT1 : (pc == 2) ? WT2
                           : (pc == 3) ? WT3 : (pc == 4) ? WT4 : WT5;
#pragma unroll
            for (int i = 0; i < L_VIEWS; ++i)
                if (m & (1 << i)) sh[i] += wt * f;
        }
        float mx = sh[0];
#pragma unroll
        for (int i = 1; i < L_VIEWS; ++i) mx = fmaxf(mx, sh[i]);
        float e[L_VIEWS];
        float sum = 0.f;
#pragma unroll
        for (int i = 0; i < L_VIEWS; ++i) { e[i] = __expf(sh[i] - mx); sum += e[i]; }
        const float inv = 1.f / sum;
        float attn_mine[L_VIEWS];
#pragma unroll
        for (int i = 0; i < L_VIEWS; ++i) attn_mine[i] = e[i] * inv;

        // Redistribute: attn[l][j] lives at lane q + 8*j.
        float attn[L_VIEWS][4];
#pragma unroll
        for (int l = 0; l < L_VIEWS; ++l)
#pragma unroll
            for (int j = 0; j < 4; ++j)
                attn[l][j] = __shfl(attn_mine[l], q + 8 * j, 64);

        // ---- Phase C: fused output straight from registers.
#pragma unroll
        for (int k = 0; k < 2; ++k) {
            const int c = (k == 0) ? cA : cB;
            float4 acc;
            acc.x = va[0][k].x * attn[0][0];
            acc.y = va[0][k].y * attn[0][1];
            acc.z = va[0][k].z * attn[0][2];
            acc.w = va[0][k].w * attn[0][3];
#pragma unroll
            for (int l = 1; l < L_VIEWS; ++l) {
                acc.x += va[l][k].x * attn[l][0];
                acc.y += va[l][k].y * attn[l][1];
                acc.z += va[l][k].z * attn[l][2];
                acc.w += va[l][k].w * attn[l][3];
            }
            *reinterpret_cast<float4*>(out + (size_t)c * NPIX + nq) = acc;
        }
    }
}

extern "C" void kernel_launch(void* const* d_in, const int* in_sizes, int n_in,
                              void* d_out, int out_size, void* d_ws, size_t ws_size,
                              hipStream_t stream) {
    const float* feats = (const float*)d_in[0];   // [5,64,128,256] fp32
    const float* w     = (const float*)d_in[1];   // [64,1] fp32
    const float* b     = (const float*)d_in[2];   // [1] fp32
    float* out         = (float*)d_out;           // [64,128,256] fp32

    // 1024 blocks x 256 threads; block owns a 32-n (128 B) window.
    shapley_fusion_kernel<<<NPIX / 32, 256, 0, stream>>>(feats, w, b, out);
}

// Round 7
// 15.595 us; speedup vs baseline: 2.1482x; 2.1482x over previous
//
#include <hip/hip_runtime.h>

// Shapley fusion: L=5 views, C=64 channels, N=128*256 spatial positions.
// f(subset) = relu(b + sum_{l in subset} d[l]) where d[l] = dot(feats[l,:,n], w)
// -- the reference's [M,N,C] subset GEMM collapses to 5 dots per pixel.
// Shapley coef for L=5 by subset size: {-, -0.6, 0.05, 1/30, 0.05, 0.2}.
//
// Round-7 = round-6 with the nontemporal store typed as a native clang
// ext_vector (HIP's float4 struct is rejected by the builtin).
// r6 changes under test: (a) Gray-code lattice -- one running subset sum
// instead of s[32], saving ~30 VGPRs; (b) __launch_bounds__(256,4) pins
// 16 waves/CU (VGPR cap 128) so ALL 4096 waves are resident in one shot
// (r4's ~160-VGPR peak allowed only 12/CU -> 1.33 straggler batches);
// (c) nontemporal store for out (never re-read).
// Diagnostics (r5): hot-pass floor 5.95us, solo 15.65us, fills prove the box
// does 6.6 TB/s -> we are occupancy/overlap-bound, not BW-bound.

constexpr int L_VIEWS = 5;
constexpr int C_CH    = 64;
constexpr int NPIX    = 128 * 256;   // 32768

typedef float floatx4 __attribute__((ext_vector_type(4)));

__global__ __launch_bounds__(256, 4)
void shapley_fusion_kernel(const float* __restrict__ feats,
                           const float* __restrict__ w,
                           const float* __restrict__ bptr,
                           float* __restrict__ out)
{
    const int tid  = threadIdx.x;
    const int h    = tid >> 6;         // wave in block (0..3): channel quarter
    const int lane = tid & 63;
    const int q    = lane & 7;         // n-quad within the 32-n window
    const int g    = (lane >> 3) & 7;  // channel group within wave
    const int win  = blockIdx.x * 32;  // 128-B aligned n window
    const int nq   = win + q * 4;
    const int cA   = h * 8 + g;        // this thread's 2 channels
    const int cB   = cA + 32;

    const float w0   = w[cA];
    const float w1   = w[cB];
    const float bias = bptr[0];

    // ---- Phase A: load 10 float4s (held in regs through the whole kernel).
    float4 va[L_VIEWS][2];
#pragma unroll
    for (int l = 0; l < L_VIEWS; ++l) {
        va[l][0] = *reinterpret_cast<const float4*>(
            feats + ((size_t)(l * C_CH + cA) * NPIX + nq));
        va[l][1] = *reinterpret_cast<const float4*>(
            feats + ((size_t)(l * C_CH + cB) * NPIX + nq));
    }

    // Partial dots over this thread's 2 channels.
    float d[L_VIEWS][4];
#pragma unroll
    for (int l = 0; l < L_VIEWS; ++l) {
        d[l][0] = va[l][0].x * w0 + va[l][1].x * w1;
        d[l][1] = va[l][0].y * w0 + va[l][1].y * w1;
        d[l][2] = va[l][0].z * w0 + va[l][1].z * w1;
        d[l][3] = va[l][0].w * w0 + va[l][1].w * w1;
    }

    // Butterfly over the 8 channel-groups (lane bits 3..5).
#pragma unroll
    for (int l = 0; l < L_VIEWS; ++l) {
#pragma unroll
        for (int j = 0; j < 4; ++j) {
            d[l][j] += __shfl_xor(d[l][j], 8, 64);
            d[l][j] += __shfl_xor(d[l][j], 16, 64);
            d[l][j] += __shfl_xor(d[l][j], 32, 64);
        }
    }

    // ---- Cross-wave exchange (2.5 KB LDS, one barrier). ----
    __shared__ float4 xl[4][8][L_VIEWS];      // [wave][quad][l] = d[l][0..3]
    if (g == 0) {
#pragma unroll
        for (int l = 0; l < L_VIEWS; ++l) {
            float4 t; t.x = d[l][0]; t.y = d[l][1]; t.z = d[l][2]; t.w = d[l][3];
            xl[h][q][l] = t;
        }
    }
    __syncthreads();

    // Each thread finalizes d only for its own j = g&3 (phase B split 4-way).
    const int jm = g & 3;
    const float* xf = reinterpret_cast<const float*>(xl);
    float dm[L_VIEWS];
#pragma unroll
    for (int l = 0; l < L_VIEWS; ++l) {
        float s = 0.f;
#pragma unroll
        for (int hh = 0; hh < 4; ++hh)
            s += xf[(((hh * 8 + q) * L_VIEWS) + l) * 4 + jm];
        dm[l] = s;
    }

    // ---- Phase B: Gray-code subset walk -> shapley -> softmax.
    // Subsets enumerated as g_t = t ^ (t>>1), t = 1..31; step t flips bit
    // ctz(t). One running sum S replaces the s[32] array (saves ~30 VGPRs).
    constexpr float WTS[6] = {0.f, -0.6f, 0.05f, 1.0f / 30.0f, 0.05f, 0.2f};

    float S = bias;
    float sh[L_VIEWS] = {0.f, 0.f, 0.f, 0.f, 0.f};
#pragma unroll
    for (int t = 1; t < 32; ++t) {
        const int gm   = t ^ (t >> 1);           // current subset (compile-time)
        const int bit  = __builtin_ctz(t);        // flipped view index
        const bool add = (gm >> bit) & 1;         // set or cleared?
        S = add ? (S + dm[bit]) : (S - dm[bit]);
        const float f  = fmaxf(S, 0.f);
        const float wt = WTS[__builtin_popcount(gm)];
#pragma unroll
        for (int i = 0; i < L_VIEWS; ++i)
            if (gm & (1 << i)) sh[i] += wt * f;   // fmac with literal wt
    }

    float mx = sh[0];
#pragma unroll
    for (int i = 1; i < L_VIEWS; ++i) mx = fmaxf(mx, sh[i]);
    float e[L_VIEWS];
    float sum = 0.f;
#pragma unroll
    for (int i = 0; i < L_VIEWS; ++i) { e[i] = __expf(sh[i] - mx); sum += e[i]; }
    const float inv = 1.f / sum;
    float attn_mine[L_VIEWS];
#pragma unroll
    for (int i = 0; i < L_VIEWS; ++i) attn_mine[i] = e[i] * inv;

    // Redistribute: attn[l][j] lives at lane q + 8*j (that lane has jm==j).
    float attn[L_VIEWS][4];
#pragma unroll
    for (int l = 0; l < L_VIEWS; ++l)
#pragma unroll
        for (int j = 0; j < 4; ++j)
            attn[l][j] = __shfl(attn_mine[l], q + 8 * j, 64);

    // ---- Phase C: fused output straight from registers (no re-read).
#pragma unroll
    for (int k = 0; k < 2; ++k) {
        const int c = (k == 0) ? cA : cB;
        floatx4 acc;
        acc.x = va[0][k].x * attn[0][0];
        acc.y = va[0][k].y * attn[0][1];
        acc.z = va[0][k].z * attn[0][2];
        acc.w = va[0][k].w * attn[0][3];
#pragma unroll
        for (int l = 1; l < L_VIEWS; ++l) {
            acc.x += va[l][k].x * attn[l][0];
            acc.y += va[l][k].y * attn[l][1];
            acc.z += va[l][k].z * attn[l][2];
            acc.w += va[l][k].w * attn[l][3];
        }
        // out is never re-read: nontemporal store (native ext_vector type).
        __builtin_nontemporal_store(acc,
            reinterpret_cast<floatx4*>(out + (size_t)c * NPIX + nq));
    }
}

extern "C" void kernel_launch(void* const* d_in, const int* in_sizes, int n_in,
                              void* d_out, int out_size, void* d_ws, size_t ws_size,
                              hipStream_t stream) {
    const float* feats = (const float*)d_in[0];   // [5,64,128,256] fp32
    const float* w     = (const float*)d_in[1];   // [64,1] fp32
    const float* b     = (const float*)d_in[2];   // [1] fp32
    float* out         = (float*)d_out;           // [64,128,256] fp32

    // 1024 blocks x 256 threads = 4096 waves; block owns a 32-n (128 B) window.
    shapley_fusion_kernel<<<NPIX / 32, 256, 0, stream>>>(feats, w, b, out);
}